// Round 1
// baseline (84.727 us; speedup 1.0000x reference)
//
#include <hip/hip_runtime.h>

// Reference reduces analytically to out = 0.5 * x:
//   y[n,c] = sum_{h,w} ifft2(ifftshift(fftshift(fft2(x))*mask)) = DC coeff of
//   masked spectrum = 0 (mask never selects shifted position (28,28)), so the
//   SE gate is sigmoid(relu(0)@w2^T) = 0.5 exactly.
// Pure memory-bound elementwise scale: 51,380,224 fp32 elems (n % 4 == 0).

__global__ __launch_bounds__(256) void half_scale_kernel(
    const float4* __restrict__ x, float4* __restrict__ out, unsigned int n4) {
    unsigned int i = blockIdx.x * blockDim.x + threadIdx.x;
    const unsigned int stride = gridDim.x * blockDim.x;
    for (; i < n4; i += stride) {
        float4 v = x[i];
        v.x *= 0.5f; v.y *= 0.5f; v.z *= 0.5f; v.w *= 0.5f;
        out[i] = v;
    }
}

extern "C" void kernel_launch(void* const* d_in, const int* in_sizes, int n_in,
                              void* d_out, int out_size, void* d_ws, size_t ws_size,
                              hipStream_t stream) {
    const float* x = (const float*)d_in[0];
    float* out = (float*)d_out;

    const unsigned int n = (unsigned int)in_sizes[0];  // 64*256*56*56 = 51,380,224
    const unsigned int n4 = n / 4;                     // divisible by 4

    const int block = 256;
    const int grid = 2048;  // 256 CUs * 8 blocks/CU, grid-stride covers the rest
    half_scale_kernel<<<grid, block, 0, stream>>>(
        (const float4*)x, (float4*)out, n4);
}

// Round 3
// 68.064 us; speedup vs baseline: 1.2448x; 1.2448x over previous
//
#include <hip/hip_runtime.h>

// Reference reduces analytically to out = 0.5 * x (masked spectrum has zero DC
// coefficient => spectral pooling y == 0 => SE gate = sigmoid(0) = 0.5).
// Pure memory-bound elementwise scale: 51,380,224 fp32 (205.5 MB in + out).
//
// Round 2 -> 3: fix compile error — __builtin_nontemporal_store needs a clang
// ext_vector_type, not HIP's class-based float4. Same plan: unroll x4
// (independent loads in flight) + nontemporal stores (no write-allocate).

typedef float f32x4 __attribute__((ext_vector_type(4)));

__global__ __launch_bounds__(256) void half_scale_kernel(
    const f32x4* __restrict__ x, f32x4* __restrict__ out, unsigned int n4) {
    const unsigned int stride = gridDim.x * blockDim.x;
    unsigned int i = blockIdx.x * blockDim.x + threadIdx.x;

    // main unrolled loop: 4 independent loads in flight, then 4 stores
    for (; i + 3u * stride < n4; i += 4u * stride) {
        f32x4 a = x[i];
        f32x4 b = x[i + stride];
        f32x4 c = x[i + 2u * stride];
        f32x4 d = x[i + 3u * stride];
        __builtin_nontemporal_store(a * 0.5f, &out[i]);
        __builtin_nontemporal_store(b * 0.5f, &out[i + stride]);
        __builtin_nontemporal_store(c * 0.5f, &out[i + 2u * stride]);
        __builtin_nontemporal_store(d * 0.5f, &out[i + 3u * stride]);
    }
    // tail
    for (; i < n4; i += stride) {
        f32x4 v = x[i];
        __builtin_nontemporal_store(v * 0.5f, &out[i]);
    }
}

extern "C" void kernel_launch(void* const* d_in, const int* in_sizes, int n_in,
                              void* d_out, int out_size, void* d_ws, size_t ws_size,
                              hipStream_t stream) {
    const float* x = (const float*)d_in[0];
    float* out = (float*)d_out;

    const unsigned int n = (unsigned int)in_sizes[0];  // 64*256*56*56 = 51,380,224
    const unsigned int n4 = n / 4;                     // divisible by 4

    const int block = 256;
    const int grid = 2048;  // 256 CUs * 8 blocks/CU
    half_scale_kernel<<<grid, block, 0, stream>>>(
        (const f32x4*)x, (f32x4*)out, n4);
}